// Round 8
// baseline (172.183 us; speedup 1.0000x reference)
//
#include <hip/hip_runtime.h>
#include <hip/hip_bf16.h>
#include <stdint.h>
#include <stddef.h>

typedef __bf16 bf16;
typedef __attribute__((ext_vector_type(4))) __bf16 bf16x4;
typedef __attribute__((ext_vector_type(8))) __bf16 bf16x8;
typedef __attribute__((ext_vector_type(4))) float f32x4;

#define BATCH 4096
#define DIM 1024
#define ODIM 1024
#define K3 3072

// workspace layout (bytes)
#define WS_CB     0           // bf16 [1024][3072] = 6291456
#define WS_BIAS   6291456     // f32  [1024]
#define WS_UMIN   6295552     // u32  [1024] order-encoded min
#define WS_UMAXC  6299648     // u32  [1024] order-encoded ~max (min of ~key)

#define ASYNC16(g, l)                                                          \
  __builtin_amdgcn_global_load_lds(                                            \
      (__attribute__((address_space(1))) void*)(g),                            \
      (__attribute__((address_space(3))) void*)(l), 16, 0, 0)

#define BARRIER()                     \
  do {                                \
    asm volatile("" ::: "memory");    \
    __builtin_amdgcn_s_barrier();     \
    asm volatile("" ::: "memory");    \
  } while (0)
// s_waitcnt imm: vmcnt[3:0]=bits3:0, expcnt=bits6:4, lgkmcnt=bits11:8, vmcnt[5:4]=bits15:14
#define WAIT_VM(n) __builtin_amdgcn_s_waitcnt(0x0F00 | 0x0070 | ((n)&15) | ((((n)>>4)&3)<<14))
#define WAIT_VM0() __builtin_amdgcn_s_waitcnt(0x0F00 | 0x0070)
#define WAIT_LGKM() __builtin_amdgcn_s_waitcnt(0xC07F)

// order-preserving f32 <-> u32 key (no NaNs in randn inputs)
__device__ __forceinline__ uint32_t enc_f32(float f) {
  uint32_t u = __float_as_uint(f);
  return (u & 0x80000000u) ? ~u : (u | 0x80000000u);
}
__device__ __forceinline__ float dec_f32(uint32_t k) {
  return __uint_as_float((k & 0x80000000u) ? (k ^ 0x80000000u) : ~k);
}

// ---- kernel 1 (FUSED): blocks 0..255  = column min/max of x via device atomics
//                        blocks 256..1279 = spline coeff reduce (independent)
// x (16.8 MB) and sp (67 MB) cold streams run CONCURRENTLY. min/max published
// via atomicMin on encoded keys -> no partials, no final-reduce kernel.
__global__ void k_stream(const float* __restrict__ x,
                         uint32_t* __restrict__ umin,
                         uint32_t* __restrict__ umaxc,
                         const float* __restrict__ sp,
                         bf16* __restrict__ CB,
                         float* __restrict__ bias) {
  __shared__ float red[4];
  const int t = threadIdx.x;
  if (blockIdx.x < 256) {
    const int ch = blockIdx.x;
    const float* p = x + (size_t)ch * 16 * DIM + (t << 2);
    f32x4 mn = {1e30f, 1e30f, 1e30f, 1e30f};
    f32x4 mx = {-1e30f, -1e30f, -1e30f, -1e30f};
#pragma unroll
    for (int r = 0; r < 16; ++r) {
      f32x4 v = *(const f32x4*)(p + (size_t)r * DIM);
#pragma unroll
      for (int j = 0; j < 4; ++j) {
        mn[j] = fminf(mn[j], v[j]);
        mx[j] = fmaxf(mx[j], v[j]);
      }
    }
    const int c = t << 2;
#pragma unroll
    for (int j = 0; j < 4; ++j) {
      atomicMin(&umin[c + j], enc_f32(mn[j]));
      atomicMin(&umaxc[c + j], ~enc_f32(mx[j]));
    }
  } else {
    const int o = blockIdx.x - 256;
    const int d = t << 2;
    f32x4 s[4];
#pragma unroll
    for (int dd = 0; dd < 4; ++dd) {
      const float* p = sp + ((size_t)o * DIM + d + dd) * 16;  // [s=4][4]
      f32x4 acc = *(const f32x4*)(p);
      acc += *(const f32x4*)(p + 4);
      acc += *(const f32x4*)(p + 8);
      acc += *(const f32x4*)(p + 12);
      s[dd] = acc;
    }
    size_t cb = (size_t)o * K3 + d;
    bf16x4 c0 = {(bf16)s[0][0], (bf16)s[1][0], (bf16)s[2][0], (bf16)s[3][0]};
    bf16x4 c1 = {(bf16)s[0][1], (bf16)s[1][1], (bf16)s[2][1], (bf16)s[3][1]};
    bf16x4 c2 = {(bf16)s[0][2], (bf16)s[1][2], (bf16)s[2][2], (bf16)s[3][2]};
    *(bf16x4*)(CB + cb) = c0;
    *(bf16x4*)(CB + cb + 1024) = c1;
    *(bf16x4*)(CB + cb + 2048) = c2;
    float v = s[0][3] + s[1][3] + s[2][3] + s[3][3];
#pragma unroll
    for (int off = 32; off > 0; off >>= 1) v += __shfl_down(v, off, 64);
    int lane = t & 63, w = t >> 6;
    if (lane == 0) red[w] = v;
    __syncthreads();
    if (t == 0) bias[o] = red[0] + red[1] + red[2] + red[3];
  }
}

// ---- kernel 2: FUSED powers+GEMM with STATIC PRODUCER/CONSUMER WAVES.
// Waves 0-3 (consumers): 64x64 quadrants, full K, 48 MFMA/tile -- LDS frag
// reads drop 33% vs 8x(64x32). Waves 4-7 (producers): normalize+powers A
// into LDS, pre-swizzled global_load_lds for B, x prefetch, ms decode.
// Each SIMD hosts 1 MFMA wave + 1 VALU/mem wave (m114 co-issue).
// 2 buffers, 1 barrier per 32-dim tile (R7's proven skeleton).
#define MSOFF 98304            // mn[1024]f32 | sc[1024]f32
#define ABUF(b) ((b) * 24576)           // A: [3][128][32] bf16 (plane 8192)
#define BBUF(b) (49152 + (b) * 24576)   // B: same shape
__global__ __launch_bounds__(512, 2) void k_gemm(const float* __restrict__ x,
                                                 const uint32_t* __restrict__ umin,
                                                 const uint32_t* __restrict__ umaxc,
                                                 const bf16* __restrict__ CBm,
                                                 const float* __restrict__ bias,
                                                 float* __restrict__ out) {
  __shared__ __attribute__((aligned(16))) char smem[106496];  // 104 KB

  const int tid = threadIdx.x;
  const int wave = tid >> 6;
  const int lane = tid & 63;

  // XCD-chunk decode: bijective map flat bid -> (mt, nt) in 32x8 tile grid
  const int f = blockIdx.x;
  const int chunk = f & 7;       // lands on XCD (f % 8)
  const int idx = f >> 3;        // 0..31 within chunk
  const int mt = ((chunk >> 1) << 3) + (idx >> 2);
  const int nt = ((chunk & 1) << 2) + (idx & 3);
  const int bm = mt * 128;
  const int bn = nt * 128;

  // consumer geometry: wave 0..3 -> 64x64 quadrant
  const int wr = ((wave & 3) >> 1) * 64;
  const int wc = (wave & 1) * 64;
  const int mrow = lane & 15;
  const int kq = lane >> 4;      // 16B unit within 32-dim K window

  // producer geometry (waves 4..7)
  const int ptid = (tid >= 256) ? (tid - 256) : 0;
  const int pr = ptid >> 1;      // A/x row 0..127
  const int h = tid & 1;         // 16-dim half of the 32-dim tile
  const int sA0 = ((h * 2 + 0) ^ ((pr >> 1) & 3)) << 4;
  const int sA1 = ((h * 2 + 1) ^ ((pr >> 1) & 3)) << 4;
  const float* xg = x + (size_t)(bm + pr) * DIM + h * 16;

  // producer B-staging: 24 wave-issues cover [3][128][32]; this wave's 6.
  // LDS linear off L = (pk*6+i)*1024 + lane*16 -> (plane,row,slot);
  // global src pre-swizzled: unit = slot ^ ((row>>1)&3).
  const char* gB[6];
  int ldsBoff[6];
  if (wave >= 4) {
    const int pk = wave - 4;
#pragma unroll
    for (int i = 0; i < 6; ++i) {
      int L = (pk * 6 + i) * 1024 + lane * 16;
      int p_ = L >> 13;
      int rem = L & 8191;
      int row_ = rem >> 6;
      int u_ = (rem >> 4) & 3;
      int us = u_ ^ ((row_ >> 1) & 3);
      gB[i] = (const char*)CBm + (size_t)(bn + row_) * 6144 + p_ * 2048 + us * 16;
      ldsBoff[i] = (pk * 6 + i) * 1024;
    }
  }

  f32x4 xA0, xA1, xA2, xA3, xB0, xB1, xB2, xB3;
#define LOADX(S, dtv)                                                         \
  do {                                                                        \
    const float* xp_ = xg + (dtv) * 32;                                       \
    S##0 = *(const f32x4*)(xp_);                                              \
    S##1 = *(const f32x4*)(xp_ + 4);                                          \
    S##2 = *(const f32x4*)(xp_ + 8);                                          \
    S##3 = *(const f32x4*)(xp_ + 12);                                         \
  } while (0)

#define STAGE_B(buf, dtv)                                                     \
  do {                                                                        \
    _Pragma("unroll") for (int i_ = 0; i_ < 6; ++i_)                          \
        ASYNC16(gB[i_] + (size_t)(dtv) * 64,                                  \
                smem + BBUF(buf) + ldsBoff[i_]);                              \
  } while (0)

#define PK8(lo, hi, dst)                                                      \
  _Pragma("unroll") for (int e_ = 0; e_ < 4; ++e_) {                          \
    dst[e_] = (bf16)lo[e_];                                                   \
    dst[e_ + 4] = (bf16)hi[e_];                                               \
  }

#define POWERS(buf, dtv, S)                                                   \
  do {                                                                        \
    const char* msp = smem + MSOFF + ((dtv) * 32 + h * 16) * 4;               \
    f32x4 n0 = (S##0 - *(const f32x4*)(msp)) * *(const f32x4*)(msp + 4096);   \
    f32x4 n1 = (S##1 - *(const f32x4*)(msp + 16)) * *(const f32x4*)(msp + 4112); \
    f32x4 n2 = (S##2 - *(const f32x4*)(msp + 32)) * *(const f32x4*)(msp + 4128); \
    f32x4 n3 = (S##3 - *(const f32x4*)(msp + 48)) * *(const f32x4*)(msp + 4144); \
    f32x4 q0 = n0 * n0, q1 = n1 * n1, q2 = n2 * n2, q3 = n3 * n3;             \
    f32x4 c0 = q0 * n0, c1 = q1 * n1, c2 = q2 * n2, c3 = q3 * n3;             \
    bf16x8 w3a, w3b, w2a, w2b, w1a, w1b;                                      \
    PK8(c0, c1, w3a) PK8(c2, c3, w3b)                                         \
    PK8(q0, q1, w2a) PK8(q2, q3, w2b)                                         \
    PK8(n0, n1, w1a) PK8(n2, n3, w1b)                                         \
    char* aw_ = smem + ABUF(buf) + pr * 64;                                   \
    *(bf16x8*)(aw_ + sA0) = w3a;                                              \
    *(bf16x8*)(aw_ + sA1) = w3b;                                              \
    *(bf16x8*)(aw_ + 8192 + sA0) = w2a;                                       \
    *(bf16x8*)(aw_ + 8192 + sA1) = w2b;                                       \
    *(bf16x8*)(aw_ + 16384 + sA0) = w1a;                                      \
    *(bf16x8*)(aw_ + 16384 + sA1) = w1b;                                      \
  } while (0)

  f32x4 acc[4][4] = {};

#define COMPUTE(buf)                                                          \
  do {                                                                        \
    const char* ab_ = smem + ABUF(buf);                                       \
    const char* bb_ = smem + BBUF(buf);                                       \
    _Pragma("unroll") for (int p = 0; p < 3; ++p) {                           \
      bf16x8 af[4], bg[4];                                                    \
      _Pragma("unroll") for (int i = 0; i < 4; ++i) {                         \
        int rowa = wr + i * 16 + mrow;                                        \
        af[i] = *(const bf16x8*)(ab_ + p * 8192 + rowa * 64 +                 \
                                 ((kq ^ ((rowa >> 1) & 3)) << 4));            \
        int rowb = wc + i * 16 + mrow;                                        \
        bg[i] = *(const bf16x8*)(bb_ + p * 8192 + rowb * 64 +                 \
                                 ((kq ^ ((rowb >> 1) & 3)) << 4));            \
      }                                                                       \
      _Pragma("unroll") for (int i = 0; i < 4; ++i)                           \
          _Pragma("unroll") for (int j = 0; j < 4; ++j)                       \
              acc[i][j] = __builtin_amdgcn_mfma_f32_16x16x32_bf16(            \
                  af[i], bg[j], acc[i][j], 0, 0, 0);                          \
    }                                                                         \
  } while (0)

  // ---- prologue ----
  if (wave >= 4) {
    // decode min/max atomics -> mn/sc table in LDS (producer threads: 4 cols each)
    const int c = (tid - 256) << 2;
    f32x4 mnv, scv;
#pragma unroll
    for (int j = 0; j < 4; ++j) {
      float mnf = dec_f32(umin[c + j]);
      float mxf = dec_f32(~umaxc[c + j]);
      mnv[j] = mnf;
      scv[j] = 1.0f / (mxf - mnf);
    }
    *(f32x4*)(smem + MSOFF + c * 4) = mnv;
    *(f32x4*)(smem + MSOFF + 4096 + c * 4) = scv;
    STAGE_B(0, 0);
    LOADX(xA, 0);
    WAIT_VM0();
    WAIT_LGKM();
  }
  BARRIER();  // ms + B(0) published
  if (wave >= 4) {
    POWERS(0, 0, xA);
    LOADX(xB, 1);
    WAIT_LGKM();
  }
  BARRIER();  // A(0) published

  // ---- main loop: 32 dim-tiles, pairs of (even, odd) ----
  for (int tt = 0; tt < 15; ++tt) {
    const int t0 = tt * 2;
    if (wave >= 4) {
      STAGE_B(1, t0 + 1);
      LOADX(xA, t0 + 2);
      POWERS(1, t0 + 1, xB);
      WAIT_VM(4);   // drain the 6 B issues; leave 4 x loads in flight
      WAIT_LGKM();
    } else {
      COMPUTE(0);
    }
    BARRIER();
    if (wave >= 4) {
      STAGE_B(0, t0 + 2);
      LOADX(xB, t0 + 3);
      POWERS(0, t0 + 2, xA);
      WAIT_VM(4);
      WAIT_LGKM();
    } else {
      COMPUTE(1);
    }
    BARRIER();
  }
  // t = 30: produce tile 31 (no more x prefetch), compute tile 30
  if (wave >= 4) {
    STAGE_B(1, 31);
    POWERS(1, 31, xB);
    WAIT_VM0();
    WAIT_LGKM();
  } else {
    COMPUTE(0);
  }
  BARRIER();

  if (wave < 4) {
    COMPUTE(1);  // tile 31
    // epilogue: C/D layout col=lane&15, row=(lane>>4)*4+reg
    const int ccol = lane & 15;
    const int crow = (lane >> 4) * 4;
#pragma unroll
    for (int j = 0; j < 4; ++j) {
      const int col = bn + wc + j * 16 + ccol;
      const float bv = bias[col];
#pragma unroll
      for (int i = 0; i < 4; ++i) {
        const int row0 = bm + wr + i * 16 + crow;
#pragma unroll
        for (int r = 0; r < 4; ++r)
          out[(size_t)(row0 + r) * ODIM + col] = acc[i][j][r] + bv;
      }
    }
  }
#undef LOADX
#undef STAGE_B
#undef PK8
#undef POWERS
#undef COMPUTE
}

extern "C" void kernel_launch(void* const* d_in, const int* in_sizes, int n_in,
                              void* d_out, int out_size, void* d_ws, size_t ws_size,
                              hipStream_t stream) {
  (void)in_sizes; (void)n_in; (void)out_size; (void)ws_size;
  const float* x = (const float*)d_in[0];
  const float* sp = (const float*)d_in[1];
  float* out = (float*)d_out;
  char* ws = (char*)d_ws;

  bf16* CBm = (bf16*)(ws + WS_CB);
  float* bias = (float*)(ws + WS_BIAS);
  uint32_t* umin = (uint32_t*)(ws + WS_UMIN);
  uint32_t* umaxc = (uint32_t*)(ws + WS_UMAXC);

  // init both key arrays to 0xFF (umin: +inf key; umaxc stores ~key so FF = -inf)
  hipMemsetAsync(ws + WS_UMIN, 0xFF, 8192, stream);
  k_stream<<<1280, 256, 0, stream>>>(x, umin, umaxc, sp, CBm, bias);
  k_gemm<<<256, 512, 0, stream>>>(x, umin, umaxc, CBm, bias, out);
}

// Round 10
// 159.204 us; speedup vs baseline: 1.0815x; 1.0815x over previous
//
#include <hip/hip_runtime.h>
#include <hip/hip_bf16.h>
#include <stdint.h>
#include <stddef.h>

typedef __bf16 bf16;
typedef __attribute__((ext_vector_type(4))) __bf16 bf16x4;
typedef __attribute__((ext_vector_type(8))) __bf16 bf16x8;
typedef __attribute__((ext_vector_type(4))) float f32x4;

#define BATCH 4096
#define DIM 1024
#define ODIM 1024
#define K3 3072

// workspace layout (bytes)
#define WS_CB     0           // bf16 [1024][3072] = 6291456
#define WS_BIAS   6291456     // f32  [1024]
#define WS_PMIN   6295552     // f32  [256][1024] = 1048576
#define WS_PMAX   7344128     // f32  [256][1024]
#define WS_MINV   8392704     // f32  [1024]
#define WS_SCALE  8396800     // f32  [1024]

#define ASYNC16(g, l)                                                          \
  __builtin_amdgcn_global_load_lds(                                            \
      (__attribute__((address_space(1))) void*)(g),                            \
      (__attribute__((address_space(3))) void*)(l), 16, 0, 0)

#define BARRIER()                     \
  do {                                \
    asm volatile("" ::: "memory");    \
    __builtin_amdgcn_s_barrier();     \
    asm volatile("" ::: "memory");    \
  } while (0)
// drain ALL vmcnt (order-safe); lgkm/exp no-wait
#define WAIT_VM0() __builtin_amdgcn_s_waitcnt(0x0F00 | 0x0070)
// drain lgkmcnt; vmcnt/expcnt no-wait
#define WAIT_LGKM() __builtin_amdgcn_s_waitcnt(0xC07F)

// ---- kernel 1 (FUSED): blocks 0..255  = per-chunk column min/max of x
//                        blocks 256..1279 = spline coeff reduce (independent)
// The two cold HBM streams (x: 16.8 MB, sp: 67 MB) run CONCURRENTLY.
__global__ void k_stream(const float* __restrict__ x,
                         float* __restrict__ pmin,
                         float* __restrict__ pmax,
                         const float* __restrict__ sp,
                         bf16* __restrict__ CB,
                         float* __restrict__ bias) {
  __shared__ float red[4];
  const int t = threadIdx.x;
  if (blockIdx.x < 256) {
    const int ch = blockIdx.x;
    const float* p = x + (size_t)ch * 16 * DIM + (t << 2);
    f32x4 mn = {1e30f, 1e30f, 1e30f, 1e30f};
    f32x4 mx = {-1e30f, -1e30f, -1e30f, -1e30f};
#pragma unroll
    for (int r = 0; r < 16; ++r) {
      f32x4 v = *(const f32x4*)(p + (size_t)r * DIM);
#pragma unroll
      for (int j = 0; j < 4; ++j) {
        mn[j] = fminf(mn[j], v[j]);
        mx[j] = fmaxf(mx[j], v[j]);
      }
    }
    *(f32x4*)(pmin + ch * DIM + (t << 2)) = mn;
    *(f32x4*)(pmax + ch * DIM + (t << 2)) = mx;
  } else {
    const int o = blockIdx.x - 256;
    const int d = t << 2;
    f32x4 s[4];
#pragma unroll
    for (int dd = 0; dd < 4; ++dd) {
      const float* p = sp + ((size_t)o * DIM + d + dd) * 16;  // [s=4][4]
      f32x4 acc = *(const f32x4*)(p);
      acc += *(const f32x4*)(p + 4);
      acc += *(const f32x4*)(p + 8);
      acc += *(const f32x4*)(p + 12);
      s[dd] = acc;
    }
    size_t cb = (size_t)o * K3 + d;
    bf16x4 c0 = {(bf16)s[0][0], (bf16)s[1][0], (bf16)s[2][0], (bf16)s[3][0]};
    bf16x4 c1 = {(bf16)s[0][1], (bf16)s[1][1], (bf16)s[2][1], (bf16)s[3][1]};
    bf16x4 c2 = {(bf16)s[0][2], (bf16)s[1][2], (bf16)s[2][2], (bf16)s[3][2]};
    *(bf16x4*)(CB + cb) = c0;
    *(bf16x4*)(CB + cb + 1024) = c1;
    *(bf16x4*)(CB + cb + 2048) = c2;
    float v = s[0][3] + s[1][3] + s[2][3] + s[3][3];
#pragma unroll
    for (int off = 32; off > 0; off >>= 1) v += __shfl_down(v, off, 64);
    int lane = t & 63, w = t >> 6;
    if (lane == 0) red[w] = v;
    __syncthreads();
    if (t == 0) bias[o] = red[0] + red[1] + red[2] + red[3];
  }
}

// ---- kernel 2: final reduce + scale (16 blocks x 4 waves, coalesced) ----
__global__ void k_minmax_final(const float* __restrict__ pmin,
                               const float* __restrict__ pmax,
                               float* __restrict__ minv,
                               float* __restrict__ scale) {
  __shared__ float smn[4][64], smx[4][64];
  const int t = threadIdx.x;
  const int lane = t & 63;
  const int w = t >> 6;
  const int col = blockIdx.x * 64 + lane;
  float mn = 1e30f, mx = -1e30f;
#pragma unroll 8
  for (int ch = w; ch < 256; ch += 4) {
    mn = fminf(mn, pmin[ch * DIM + col]);
    mx = fmaxf(mx, pmax[ch * DIM + col]);
  }
  smn[w][lane] = mn;
  smx[w][lane] = mx;
  __syncthreads();
  if (w == 0) {
    mn = fminf(fminf(smn[0][lane], smn[1][lane]), fminf(smn[2][lane], smn[3][lane]));
    mx = fmaxf(fmaxf(smx[0][lane], smx[1][lane]), fmaxf(smx[2][lane], smx[3][lane]));
    minv[col] = mn;
    scale[col] = 1.0f / (mx - mn);
  }
}

// ---- kernel 3: FUSED powers+GEMM, 128x64 tile, grid 512 = 2 blocks/CU.
// R8: fused gemm is STALL-bound at 1 block/CU (MfmaUtil 19%, nothing
// saturated). This keeps R9's geometry (2 independent blocks/CU for
// cross-block TLP) but restores R7's PROVEN schedule: B double-buffered
// (12 KB/buf at BN=64), STAGE issued before COMPUTE (full compute of
// latency cover), single order-safe WAIT_VM0 drain per tile. R9's counted
// WAIT_VM(4) over a mixed vmcnt queue was the correctness bug: vmcnt
// follows ISSUE order and the compiler may hoist plain x-loads above
// global_load_lds, leaving B in flight across the barrier.
// LDS: A 2x24K + B 2x12K + ms 8K = 81920 B = exactly 160K/2.
#define ABUF(b) ((b) * 24576)           // A: [3][128][32] bf16, plane 8192
#define BBUF(b) (49152 + (b) * 12288)   // B: [3][64][32] bf16, plane 4096
#define MSOFF   73728                   // mn[1024]f32 | sc[1024]f32
__global__ __launch_bounds__(256, 2) void k_gemm(const float* __restrict__ x,
                                                 const float* __restrict__ minv,
                                                 const float* __restrict__ scale,
                                                 const bf16* __restrict__ CBm,
                                                 const float* __restrict__ bias,
                                                 float* __restrict__ out) {
  __shared__ __attribute__((aligned(16))) char smem[81920];  // 80 KB

  const int tid = threadIdx.x;
  const int wave = tid >> 6;
  const int lane = tid & 63;

  // XCD-chunk decode: 512 blocks -> (mt, nt) in 32x16 tile grid; chunk = 8Mx8N
  const int f = blockIdx.x;
  const int chunk = f & 7;       // lands on XCD (f % 8)
  const int idx = f >> 3;        // 0..63 within chunk
  const int mt = ((chunk >> 1) << 3) + (idx >> 3);
  const int nt = ((chunk & 1) << 3) + (idx & 7);
  const int bm = mt * 128;
  const int bn = nt * 64;

  const int wr = (wave >> 1) * 64;  // wave row origin: 0 or 64
  const int wc = (wave & 1) * 32;   // wave col origin: 0 or 32
  const int mrow = lane & 15;
  const int kq = lane >> 4;         // 16B unit within 32-dim K window

  // powers-producer mapping: 2 threads per row, 16 dims each
  const int pr = tid >> 1;          // row 0..127
  const int h = tid & 1;            // 16-dim half
  const int sA0 = ((h * 2 + 0) ^ ((pr >> 1) & 3)) << 4;
  const int sA1 = ((h * 2 + 1) ^ ((pr >> 1) & 3)) << 4;
  const float* xg = x + (size_t)(bm + pr) * DIM + h * 16;

  // B staging: 3 issues/thread (one per plane); LDS row = tid>>2, unit = tid&3;
  // global unit pre-swizzled: us = u ^ ((row>>1)&3). LDS dest linear.
  const int brow = tid >> 2;
  const int bus = (tid & 3) ^ ((tid >> 3) & 3);
  const char* gB = (const char*)CBm + (size_t)(bn + brow) * 6144 + bus * 16;
  const int ldsB = wave * 1024;  // wave-uniform; HW adds lane*16

  f32x4 xv0, xv1, xv2, xv3;
#define LOADX(dtv)                                                            \
  do {                                                                        \
    const float* xp_ = xg + (dtv) * 32;                                       \
    xv0 = *(const f32x4*)(xp_);                                               \
    xv1 = *(const f32x4*)(xp_ + 4);                                           \
    xv2 = *(const f32x4*)(xp_ + 8);                                           \
    xv3 = *(const f32x4*)(xp_ + 12);                                          \
  } while (0)

#define STAGE_B(buf, dtv)                                                     \
  do {                                                                        \
    const char* gb_ = gB + (size_t)(dtv) * 64;                                \
    char* lb_ = smem + BBUF(buf) + ldsB;                                      \
    ASYNC16(gb_, lb_);                                                        \
    ASYNC16(gb_ + 2048, lb_ + 4096);                                          \
    ASYNC16(gb_ + 4096, lb_ + 8192);                                          \
  } while (0)

#define PK8(lo, hi, dst)                                                      \
  _Pragma("unroll") for (int e_ = 0; e_ < 4; ++e_) {                          \
    dst[e_] = (bf16)lo[e_];                                                   \
    dst[e_ + 4] = (bf16)hi[e_];                                               \
  }

#define POWERS(buf, dtv)                                                      \
  do {                                                                        \
    const char* msp = smem + MSOFF + ((dtv) * 32 + h * 16) * 4;               \
    f32x4 n0 = (xv0 - *(const f32x4*)(msp)) * *(const f32x4*)(msp + 4096);    \
    f32x4 n1 = (xv1 - *(const f32x4*)(msp + 16)) * *(const f32x4*)(msp + 4112); \
    f32x4 n2 = (xv2 - *(const f32x4*)(msp + 32)) * *(const f32x4*)(msp + 4128); \
    f32x4 n3 = (xv3 - *(const f32x4*)(msp + 48)) * *(const f32x4*)(msp + 4144); \
    f32x4 q0 = n0 * n0, q1 = n1 * n1, q2 = n2 * n2, q3 = n3 * n3;             \
    f32x4 c0 = q0 * n0, c1 = q1 * n1, c2 = q2 * n2, c3 = q3 * n3;             \
    bf16x8 w3a, w3b, w2a, w2b, w1a, w1b;                                      \
    PK8(c0, c1, w3a) PK8(c2, c3, w3b)                                         \
    PK8(q0, q1, w2a) PK8(q2, q3, w2b)                                         \
    PK8(n0, n1, w1a) PK8(n2, n3, w1b)                                         \
    char* aw_ = smem + ABUF(buf) + pr * 64;                                   \
    *(bf16x8*)(aw_ + sA0) = w3a;                                              \
    *(bf16x8*)(aw_ + sA1) = w3b;                                              \
    *(bf16x8*)(aw_ + 8192 + sA0) = w2a;                                       \
    *(bf16x8*)(aw_ + 8192 + sA1) = w2b;                                       \
    *(bf16x8*)(aw_ + 16384 + sA0) = w1a;                                      \
    *(bf16x8*)(aw_ + 16384 + sA1) = w1b;                                      \
  } while (0)

  f32x4 acc[4][2] = {};

#define COMPUTE(buf)                                                          \
  do {                                                                        \
    const char* ab_ = smem + ABUF(buf);                                       \
    const char* bb_ = smem + BBUF(buf);                                       \
    _Pragma("unroll") for (int p = 0; p < 3; ++p) {                           \
      bf16x8 af[4], bg[2];                                                    \
      _Pragma("unroll") for (int j = 0; j < 2; ++j) {                         \
        int rowb = wc + j * 16 + mrow;                                        \
        bg[j] = *(const bf16x8*)(bb_ + p * 4096 + rowb * 64 +                 \
                                 ((kq ^ ((rowb >> 1) & 3)) << 4));            \
      }                                                                       \
      _Pragma("unroll") for (int i = 0; i < 4; ++i) {                         \
        int rowa = wr + i * 16 + mrow;                                        \
        af[i] = *(const bf16x8*)(ab_ + p * 8192 + rowa * 64 +                 \
                                 ((kq ^ ((rowa >> 1) & 3)) << 4));            \
      }                                                                       \
      _Pragma("unroll") for (int i = 0; i < 4; ++i)                           \
          _Pragma("unroll") for (int j = 0; j < 2; ++j)                       \
              acc[i][j] = __builtin_amdgcn_mfma_f32_16x16x32_bf16(            \
                  af[i], bg[j], acc[i][j], 0, 0, 0);                          \
    }                                                                         \
  } while (0)

  // ---- prologue ----
  {
    f32x4 m = *(const f32x4*)(minv + tid * 4);
    f32x4 s = *(const f32x4*)(scale + tid * 4);
    *(f32x4*)(smem + MSOFF + tid * 16) = m;
    *(f32x4*)(smem + MSOFF + 4096 + tid * 16) = s;
  }
  STAGE_B(0, 0);
  LOADX(0);
  WAIT_VM0();   // B(0) + x(0) drained
  WAIT_LGKM();  // ms ds_writes drained
  BARRIER();    // ms + B(0) published
  POWERS(0, 0);
  LOADX(1);
  WAIT_LGKM();
  BARRIER();    // A(0) published

  // ---- main loop: 32 dim-tiles, R7 schedule (1 barrier/tile, drain-all) ----
#pragma unroll 2
  for (int dt = 0; dt < 32; ++dt) {
    const int cur = dt & 1;
    if (dt < 31) STAGE_B(cur ^ 1, dt + 1);  // issue-early: covered by COMPUTE
    COMPUTE(cur);
    if (dt < 31) {
      POWERS(cur ^ 1, dt + 1);   // consumes x(dt+1) regs
      WAIT_VM0();                // B(dt+1) drained (order-safe full drain)
      if (dt < 30) LOADX(dt + 2);// next x tile; consumed next iter
      WAIT_LGKM();               // own A ds_writes drained
      BARRIER();                 // A(dt+1), B(dt+1) published
    }
  }

  // epilogue: C/D layout col=lane&15, row=(lane>>4)*4+reg
  const int ccol = lane & 15;
  const int crow = (lane >> 4) * 4;
#pragma unroll
  for (int j = 0; j < 2; ++j) {
    const int col = bn + wc + j * 16 + ccol;
    const float bv = bias[col];
#pragma unroll
    for (int i = 0; i < 4; ++i) {
      const int row0 = bm + wr + i * 16 + crow;
#pragma unroll
      for (int r = 0; r < 4; ++r)
        out[(size_t)(row0 + r) * ODIM + col] = acc[i][j][r] + bv;
    }
  }
#undef LOADX
#undef STAGE_B
#undef PK8
#undef POWERS
#undef COMPUTE
}

extern "C" void kernel_launch(void* const* d_in, const int* in_sizes, int n_in,
                              void* d_out, int out_size, void* d_ws, size_t ws_size,
                              hipStream_t stream) {
  (void)in_sizes; (void)n_in; (void)out_size; (void)ws_size;
  const float* x = (const float*)d_in[0];
  const float* sp = (const float*)d_in[1];
  float* out = (float*)d_out;
  char* ws = (char*)d_ws;

  bf16* CBm = (bf16*)(ws + WS_CB);
  float* bias = (float*)(ws + WS_BIAS);
  float* pmin = (float*)(ws + WS_PMIN);
  float* pmax = (float*)(ws + WS_PMAX);
  float* minv = (float*)(ws + WS_MINV);
  float* scale = (float*)(ws + WS_SCALE);

  // k_stream overlaps the two independent cold HBM reads (x and sp)
  k_stream<<<1280, 256, 0, stream>>>(x, pmin, pmax, sp, CBm, bias);
  k_minmax_final<<<16, 256, 0, stream>>>(pmin, pmax, minv, scale);
  k_gemm<<<512, 256, 0, stream>>>(x, minv, scale, CBm, bias, out);
}

// Round 11
// 150.587 us; speedup vs baseline: 1.1434x; 1.0572x over previous
//
#include <hip/hip_runtime.h>
#include <hip/hip_bf16.h>
#include <stdint.h>
#include <stddef.h>

typedef __bf16 bf16;
typedef __attribute__((ext_vector_type(4))) __bf16 bf16x4;
typedef __attribute__((ext_vector_type(8))) __bf16 bf16x8;
typedef __attribute__((ext_vector_type(4))) float f32x4;

#define BATCH 4096
#define DIM 1024
#define ODIM 1024
#define K3 3072

// workspace layout (bytes) — P intermediate eliminated (powers fused into GEMM)
#define WS_CB     0           // bf16 [1024][3072] = 6291456
#define WS_BIAS   6291456     // f32  [1024]
#define WS_PMIN   6295552     // f32  [256][1024] = 1048576
#define WS_PMAX   7344128     // f32  [256][1024]
#define WS_MINV   8392704     // f32  [1024]
#define WS_SCALE  8396800     // f32  [1024]

#define ASYNC16(g, l)                                                          \
  __builtin_amdgcn_global_load_lds(                                            \
      (__attribute__((address_space(1))) void*)(g),                            \
      (__attribute__((address_space(3))) void*)(l), 16, 0, 0)

#define BARRIER()                     \
  do {                                \
    asm volatile("" ::: "memory");    \
    __builtin_amdgcn_s_barrier();     \
    asm volatile("" ::: "memory");    \
  } while (0)
// wait all vmcnt; lgkm/exp no-wait: vm[3:0]=0,exp=7,lgkm=15,vm[5:4]=0
#define WAIT_VM0() __builtin_amdgcn_s_waitcnt(0x0F00 | 0x0070)
// wait lgkmcnt(0); vmcnt/expcnt no-wait
#define WAIT_LGKM() __builtin_amdgcn_s_waitcnt(0xC07F)

// ---- kernel 1 (FUSED): blocks 0..255  = per-chunk column min/max of x
//                        blocks 256..1279 = spline coeff reduce (independent)
// The two cold HBM streams (x: 16.8 MB, sp: 67 MB) run CONCURRENTLY.
__global__ void k_stream(const float* __restrict__ x,
                         float* __restrict__ pmin,
                         float* __restrict__ pmax,
                         const float* __restrict__ sp,
                         bf16* __restrict__ CB,
                         float* __restrict__ bias) {
  __shared__ float red[4];
  const int t = threadIdx.x;
  if (blockIdx.x < 256) {
    const int ch = blockIdx.x;
    const float* p = x + (size_t)ch * 16 * DIM + (t << 2);
    f32x4 mn = {1e30f, 1e30f, 1e30f, 1e30f};
    f32x4 mx = {-1e30f, -1e30f, -1e30f, -1e30f};
#pragma unroll
    for (int r = 0; r < 16; ++r) {
      f32x4 v = *(const f32x4*)(p + (size_t)r * DIM);
#pragma unroll
      for (int j = 0; j < 4; ++j) {
        mn[j] = fminf(mn[j], v[j]);
        mx[j] = fmaxf(mx[j], v[j]);
      }
    }
    *(f32x4*)(pmin + ch * DIM + (t << 2)) = mn;
    *(f32x4*)(pmax + ch * DIM + (t << 2)) = mx;
  } else {
    const int o = blockIdx.x - 256;
    const int d = t << 2;
    f32x4 s[4];
#pragma unroll
    for (int dd = 0; dd < 4; ++dd) {
      const float* p = sp + ((size_t)o * DIM + d + dd) * 16;  // [s=4][4]
      f32x4 acc = *(const f32x4*)(p);
      acc += *(const f32x4*)(p + 4);
      acc += *(const f32x4*)(p + 8);
      acc += *(const f32x4*)(p + 12);
      s[dd] = acc;
    }
    size_t cb = (size_t)o * K3 + d;
    bf16x4 c0 = {(bf16)s[0][0], (bf16)s[1][0], (bf16)s[2][0], (bf16)s[3][0]};
    bf16x4 c1 = {(bf16)s[0][1], (bf16)s[1][1], (bf16)s[2][1], (bf16)s[3][1]};
    bf16x4 c2 = {(bf16)s[0][2], (bf16)s[1][2], (bf16)s[2][2], (bf16)s[3][2]};
    *(bf16x4*)(CB + cb) = c0;
    *(bf16x4*)(CB + cb + 1024) = c1;
    *(bf16x4*)(CB + cb + 2048) = c2;
    float v = s[0][3] + s[1][3] + s[2][3] + s[3][3];
#pragma unroll
    for (int off = 32; off > 0; off >>= 1) v += __shfl_down(v, off, 64);
    int lane = t & 63, w = t >> 6;
    if (lane == 0) red[w] = v;
    __syncthreads();
    if (t == 0) bias[o] = red[0] + red[1] + red[2] + red[3];
  }
}

// ---- kernel 2: final reduce + scale (16 blocks x 4 waves, coalesced) ----
__global__ void k_minmax_final(const float* __restrict__ pmin,
                               const float* __restrict__ pmax,
                               float* __restrict__ minv,
                               float* __restrict__ scale) {
  __shared__ float smn[4][64], smx[4][64];
  const int t = threadIdx.x;
  const int lane = t & 63;
  const int w = t >> 6;
  const int col = blockIdx.x * 64 + lane;
  float mn = 1e30f, mx = -1e30f;
#pragma unroll 8
  for (int ch = w; ch < 256; ch += 4) {
    mn = fminf(mn, pmin[ch * DIM + col]);
    mx = fmaxf(mx, pmax[ch * DIM + col]);
  }
  smn[w][lane] = mn;
  smx[w][lane] = mx;
  __syncthreads();
  if (w == 0) {
    mn = fminf(fminf(smn[0][lane], smn[1][lane]), fminf(smn[2][lane], smn[3][lane]));
    mx = fmaxf(fmaxf(smx[0][lane], smx[1][lane]), fmaxf(smx[2][lane], smx[3][lane]));
    minv[col] = mn;
    scale[col] = 1.0f / (mx - mn);
  }
}

// ---- kernel 3: FUSED powers+GEMM, staged B.  (R7 configuration — measured
// best, 151.5 us total; re-banked after R8/R10 structural alternatives both
// regressed.)
// out[b][o] = sum_p sum_d pow_p(xn[b][d]) * CB[o][p*1024+d] + bias[o]
// 128x128 tile, 8 waves, wave tile 64x32. 32 dim-tiles of 32 dims.
// Per tile: A=[3][128][32]bf16 generated in-register from x (fused powers);
// B=[3][128][32] staged via global_load_lds issued BEFORE compute (full
// compute phase of latency cover); single order-safe drain-all per tile;
// both A and B double-buffered; ONE barrier per dim-tile.
#define MSOFF 98304            // minv[1024]f32 | scale[1024]f32
#define ABUF(b) ((b) * 24576)          // [3][128][32] bf16, plane stride 8192
#define BBUF(b) (49152 + (b) * 24576)
__global__ __launch_bounds__(512, 2) void k_gemm(const float* __restrict__ x,
                                                 const float* __restrict__ minv,
                                                 const float* __restrict__ scale,
                                                 const bf16* __restrict__ CBm,
                                                 const float* __restrict__ bias,
                                                 float* __restrict__ out) {
  __shared__ __attribute__((aligned(16))) char smem[106496];  // 104 KB

  const int tid = threadIdx.x;
  const int wave = tid >> 6;
  const int lane = tid & 63;

  // XCD-chunk decode: bijective map flat bid -> (mt, nt) in 32x8 tile grid
  const int f = blockIdx.x;
  const int chunk = f & 7;       // lands on XCD (f % 8)
  const int idx = f >> 3;        // 0..31 within chunk
  const int mt = ((chunk >> 1) << 3) + (idx >> 2);
  const int nt = ((chunk & 1) << 2) + (idx & 3);
  const int bm = mt * 128;
  const int bn = nt * 128;

  const int wr = (wave >> 2) * 64;  // wave row origin (M): 0 or 64
  const int wc = (wave & 3) * 32;   // wave col origin (N): 0..96
  const int mrow = lane & 15;
  const int kq = lane >> 4;         // 16B unit within the 32-dim K window

  // producer mapping: thread -> (row prow, 8-dim group u)
  const int prow = tid >> 2;        // 0..127
  const int u = tid & 3;            // 0..3
  const int aslot = (u ^ ((prow >> 1) & 3)) << 4;  // swizzled byte slot
  const float* xg = x + (size_t)(bm + prow) * DIM + u * 8;

  // B staging: thread covers LDS (row=tid>>2, slot=tid&3); global unit = slot ^ ((row>>1)&3)
  const char* gBp = (const char*)CBm + (size_t)(bn + (tid >> 2)) * 6144 +
                    (size_t)(((tid & 3) ^ ((tid >> 3) & 3)) << 4);

  // stage minv|scale into LDS (8 KB)
  if (tid < 256) {
    f32x4 m = *(const f32x4*)(minv + tid * 4);
    *(f32x4*)(smem + MSOFF + tid * 16) = m;
  } else {
    f32x4 s = *(const f32x4*)(scale + (tid - 256) * 4);
    *(f32x4*)(smem + MSOFF + 4096 + (tid - 256) * 16) = s;
  }

  f32x4 xa, xb;
#define LOADX(dtv)                                                            \
  do {                                                                        \
    xa = *(const f32x4*)(xg + (dtv) * 32);                                    \
    xb = *(const f32x4*)(xg + (dtv) * 32 + 4);                                \
  } while (0)

#define STAGE_B(buf, dtv)                                                     \
  do {                                                                        \
    const char* gb_ = gBp + (size_t)(dtv) * 64;                               \
    char* lb_ = smem + BBUF(buf) + wave * 1024;                               \
    ASYNC16(gb_, lb_);                                                        \
    ASYNC16(gb_ + 2048, lb_ + 8192);                                          \
    ASYNC16(gb_ + 4096, lb_ + 16384);                                         \
  } while (0)

#define POWERS_WRITE(abuf, dtv)                                               \
  do {                                                                        \
    const char* msp = smem + MSOFF + ((dtv) * 32 + u * 8) * 4;                \
    f32x4 mn0 = *(const f32x4*)(msp);                                         \
    f32x4 mn1 = *(const f32x4*)(msp + 16);                                    \
    f32x4 sc0 = *(const f32x4*)(msp + 4096);                                  \
    f32x4 sc1 = *(const f32x4*)(msp + 4112);                                  \
    f32x4 n0 = (xa - mn0) * sc0, n1 = (xb - mn1) * sc1;                       \
    f32x4 q0 = n0 * n0, q1 = n1 * n1;                                         \
    f32x4 c0v = q0 * n0, c1v = q1 * n1;                                       \
    bf16x8 w1, w2, w3;                                                        \
    _Pragma("unroll") for (int e = 0; e < 4; ++e) {                           \
      w3[e] = (bf16)c0v[e]; w3[e + 4] = (bf16)c1v[e];                         \
      w2[e] = (bf16)q0[e];  w2[e + 4] = (bf16)q1[e];                          \
      w1[e] = (bf16)n0[e];  w1[e + 4] = (bf16)n1[e];                          \
    }                                                                         \
    char* aw_ = smem + ABUF(abuf) + prow * 64 + aslot;                        \
    *(bf16x8*)(aw_) = w3;              /* plane 0: x^3 */                     \
    *(bf16x8*)(aw_ + 8192) = w2;       /* plane 1: x^2 */                     \
    *(bf16x8*)(aw_ + 16384) = w1;      /* plane 2: x   */                     \
  } while (0)

  f32x4 acc[4][2] = {};

#define COMPUTE(buf)                                                          \
  do {                                                                        \
    const char* ab_ = smem + ABUF(buf);                                       \
    const char* bb_ = smem + BBUF(buf);                                       \
    _Pragma("unroll") for (int p = 0; p < 3; ++p) {                           \
      bf16x8 bg[2];                                                           \
      _Pragma("unroll") for (int j = 0; j < 2; ++j) {                         \
        int rowb = wc + j * 16 + mrow;                                        \
        bg[j] = *(const bf16x8*)(bb_ + p * 8192 + rowb * 64 +                 \
                                 ((kq ^ ((rowb >> 1) & 3)) << 4));            \
      }                                                                       \
      bf16x8 af[4];                                                           \
      _Pragma("unroll") for (int i = 0; i < 4; ++i) {                         \
        int rowa = wr + i * 16 + mrow;                                        \
        af[i] = *(const bf16x8*)(ab_ + p * 8192 + rowa * 64 +                 \
                                 ((kq ^ ((rowa >> 1) & 3)) << 4));            \
      }                                                                       \
      _Pragma("unroll") for (int i = 0; i < 4; ++i)                           \
          _Pragma("unroll") for (int j = 0; j < 2; ++j)                       \
              acc[i][j] = __builtin_amdgcn_mfma_f32_16x16x32_bf16(            \
                  af[i], bg[j], acc[i][j], 0, 0, 0);                          \
    }                                                                         \
  } while (0)

  // prologue
  STAGE_B(0, 0);     // 3 vm
  LOADX(0);          // 2 vm
  WAIT_VM0();        // B(0)+x(0) drained (B had full issue-to-here window)
  WAIT_LGKM();       // ms writes drained
  BARRIER();         // ms + B(0) published
  POWERS_WRITE(0, 0);
  LOADX(1);
  WAIT_LGKM();
  BARRIER();         // A(0) published

#pragma unroll 2
  for (int dt = 0; dt < 32; ++dt) {
    if (dt < 31) STAGE_B((dt + 1) & 1, dt + 1);  // issue-early: covered by COMPUTE
    COMPUTE(dt & 1);
    if (dt < 31) POWERS_WRITE((dt + 1) & 1, dt + 1);  // consumes x(dt+1) regs
    WAIT_VM0();                     // B(dt+1) drained (issued ~1 compute ago)
    if (dt < 30) LOADX(dt + 2);     // next x tile; consumed next iter
    WAIT_LGKM();                    // own A ds_writes drained
    BARRIER();                      // A(dt+1), B(dt+1) published
  }

  // epilogue: C/D layout col=lane&15, row=(lane>>4)*4+reg
  const int ccol = lane & 15;
  const int crow = (lane >> 4) * 4;
#pragma unroll
  for (int j = 0; j < 2; ++j) {
    const int col = bn + wc + j * 16 + ccol;
    const float bv = bias[col];
#pragma unroll
    for (int i = 0; i < 4; ++i) {
      const int row0 = bm + wr + i * 16 + crow;
#pragma unroll
      for (int r = 0; r < 4; ++r)
        out[(size_t)(row0 + r) * ODIM + col] = acc[i][j][r] + bv;
    }
  }
#undef LOADX
#undef STAGE_B
#undef POWERS_WRITE
#undef COMPUTE
}

extern "C" void kernel_launch(void* const* d_in, const int* in_sizes, int n_in,
                              void* d_out, int out_size, void* d_ws, size_t ws_size,
                              hipStream_t stream) {
  (void)in_sizes; (void)n_in; (void)out_size; (void)ws_size;
  const float* x = (const float*)d_in[0];
  const float* sp = (const float*)d_in[1];
  float* out = (float*)d_out;
  char* ws = (char*)d_ws;

  bf16* CBm = (bf16*)(ws + WS_CB);
  float* bias = (float*)(ws + WS_BIAS);
  float* pmin = (float*)(ws + WS_PMIN);
  float* pmax = (float*)(ws + WS_PMAX);
  float* minv = (float*)(ws + WS_MINV);
  float* scale = (float*)(ws + WS_SCALE);

  // k_stream overlaps the two independent cold HBM reads (x and sp)
  k_stream<<<1280, 256, 0, stream>>>(x, pmin, pmax, sp, CBm, bias);
  k_minmax_final<<<16, 256, 0, stream>>>(pmin, pmax, minv, scale);
  k_gemm<<<256, 512, 0, stream>>>(x, minv, scale, CBm, bias, out);
}